// Round 9
// baseline (202.225 us; speedup 1.0000x reference)
//
#include <hip/hip_runtime.h>
#include <stdint.h>
#include <math.h>

// Problem constants
constexpr int Kk  = 1024;

// d_out layout (floats)
constexpr int OUT0_N   = 32 * 64 * 1024;       // 2097152 (z_st, [B,D,H,W])
constexpr int OUT_LOSS = OUT0_N;               // 2097152
constexpr int OUT_PERP = OUT0_N + 1;           // 2097153
constexpr int OUT_ENC  = OUT0_N + 2;           // 2097154

// d_ws layout (bytes) — everything fully written each call (ws is poisoned):
//   [0      .. 4096)      counts u32[1024]     (zeroed by norms block 0)
//   [4096   .. 12288)     loss partials double[1024] (finish)
//   [12288  .. 16384)     Bn_g f32[1024]       exact code norms (norms_kernel)
//   [16384  .. 16416)     maxbn f32[8]         PER-CG max code norm
//   [20480  .. 151552)    ebf16 128KB          bf16 emb, swizzled per-cg tile
//                         image (norms_kernel; dist does a LINEAR copy to LDS)
//   [151552 .. 2248704)   lockey u64[32768][8] per-(row,cg): {local-min f32 hi,
//                         cnt+3x10b candidate codes lo} — PLAIN stores.
// R13: (1) bf16 conversion hoisted to norms (was redone 256x per cg);
//      (2) dist occupancy 4->5 blocks/CU; (3) finish: vectorized exact_key
//      gathers + OVF scans restricted to the OVF'd cg's 128 codes (R11
//      showed exact_key divergent gathers are the finish cost).
constexpr size_t WS_CNT = 0;
constexpr size_t WS_LP  = 4096;
constexpr size_t WS_BN  = 12288;
constexpr size_t WS_MBN = 16384;
constexpr size_t WS_EBF = 20480;
constexpr size_t WS_KEY = 151552;

typedef short bf16x8 __attribute__((ext_vector_type(8)));
typedef float f32x16 __attribute__((ext_vector_type(16)));

// ---------------------------------------------------------------------------
// numpy-bit-exact 64-elem squared-norm: tt[d]=fl(x*x), 8 stride-8 sequential
// accumulators, pairwise combine. Contraction OFF. p: 16B-aligned, contiguous.
// ---------------------------------------------------------------------------
__device__ __forceinline__ float norm64v(const float4* __restrict__ p) {
#pragma clang fp contract(off)
    float tt[64];
#pragma unroll
    for (int q = 0; q < 16; ++q) {
        float4 v = p[q];
        tt[4 * q + 0] = v.x * v.x;
        tt[4 * q + 1] = v.y * v.y;
        tt[4 * q + 2] = v.z * v.z;
        tt[4 * q + 3] = v.w * v.w;
    }
    float r[8];
#pragma unroll
    for (int j = 0; j < 8; ++j) r[j] = tt[j];
#pragma unroll
    for (int i = 8; i < 64; i += 8)
#pragma unroll
        for (int j = 0; j < 8; ++j) r[j] += tt[i + j];
    return ((r[0] + r[1]) + (r[2] + r[3])) + ((r[4] + r[5]) + (r[6] + r[7]));
}

__device__ __forceinline__ uint32_t fsort(float f) {
    uint32_t b = __float_as_uint(f);
    return (b & 0x80000000u) ? ~b : (b | 0x80000000u);
}

// RNE float->bf16 (finite inputs only; data is well inside normal range)
__device__ __forceinline__ unsigned short f2bf(float f) {
    uint32_t u = __float_as_uint(f);
    uint32_t r = (u + 0x7fffu + ((u >> 16) & 1u)) >> 16;
    return (unsigned short)r;
}

// exact distance key, bit-identical arithmetic to R5/R7 (C = ascending-d
// sequential fma chain, single accumulator; dist = fl(fl(A+B)-2C)).
// R13: emb row loaded as 16 independent float4s up front — the FMA ORDER is
// unchanged (still d=0..63 ascending into one accumulator), only the load
// scheduling improves (R11 lesson: scalar divergent gathers dominate).
__device__ __forceinline__ unsigned long long
exact_key_bn(float A, const float* __restrict__ xr, const float* __restrict__ emb,
             const float* __restrict__ Bn_g, uint32_t code) {
    const float4* e4 = (const float4*)(emb + (size_t)code * 64);
    float4 ev[16];
#pragma unroll
    for (int q = 0; q < 16; ++q) ev[q] = e4[q];
    float C = 0.f;
#pragma unroll
    for (int q = 0; q < 16; ++q) {
        C = __builtin_fmaf(xr[4 * q + 0], ev[q].x, C);
        C = __builtin_fmaf(xr[4 * q + 1], ev[q].y, C);
        C = __builtin_fmaf(xr[4 * q + 2], ev[q].z, C);
        C = __builtin_fmaf(xr[4 * q + 3], ev[q].w, C);
    }
    float s = A + Bn_g[code];
    float dist = __builtin_fmaf(-2.f, C, s);
    return ((unsigned long long)fsort(dist) << 32) | code;
}

// ---------------------------------------------------------------------------
// norms_kernel: 4 blocks x 256 thr — per code: exact norm (norm64v, once),
// bf16 conversion + swizzled tile image into ws (byte-identical to what dist
// previously built in LDS itself, 256x redundantly), per-cg max norms,
// counts zero.
// ---------------------------------------------------------------------------
__global__ __launch_bounds__(256)
void norms_kernel(const float* __restrict__ emb, float* __restrict__ Bn_g,
                  float* __restrict__ maxbn, uint32_t* __restrict__ counts,
                  unsigned char* __restrict__ ebf16g) {
    __shared__ float wred[4];
    const int t = threadIdx.x, lane = t & 63, wv = t >> 6;
    const int code = blockIdx.x * 256 + t;
    float nn = norm64v((const float4*)(emb + (size_t)code * 64));
    Bn_g[code] = nn;
    if (blockIdx.x == 0) ((uint4*)counts)[t] = make_uint4(0u, 0u, 0u, 0u);

    // bf16 swizzled tile image: tile = code>>7, row lc = code&127,
    // byte-in-row = (q*8) ^ ((lc&7)<<4)  [identical to R12's LDS build]
    {
        unsigned char* base = ebf16g + (size_t)(code >> 7) * 16384 + (size_t)(code & 127) * 128;
        const int swz = (code & 7) << 4;
        const float4* e4 = (const float4*)(emb + (size_t)code * 64);
#pragma unroll
        for (int q = 0; q < 16; ++q) {
            float4 v = e4[q];
            ushort4 bv;
            bv.x = f2bf(v.x); bv.y = f2bf(v.y); bv.z = f2bf(v.z); bv.w = f2bf(v.w);
            *(ushort4*)(base + ((q * 8) ^ swz)) = bv;
        }
    }
    float mx = nn;
#pragma unroll
    for (int m = 1; m < 64; m <<= 1) mx = fmaxf(mx, __shfl_xor(mx, m, 64));
    if (lane == 0) wred[wv] = mx;
    __syncthreads();
    if (t == 0)   maxbn[blockIdx.x * 2 + 0] = fmaxf(wred[0], wred[1]);
    if (t == 128) maxbn[blockIdx.x * 2 + 1] = fmaxf(wred[2], wred[3]);
}

// ---------------------------------------------------------------------------
// dist_mfma (R13): 2048 blocks = 256 rowgroups x 8 codegroups, 256 thr,
// ~17 KB LDS, 5 blocks/CU (launch_bounds(256,5); VGPR budget 102).
// Screen: s_hat = Bn_exact - 2*(x.e)_bf16 via mfma_32x32x16_bf16; margin
// 0.017*sqrt(xsq*maxBn_cg)+1e-4 (validated R6/R8/R9/R12, absmax 0.0 each).
// e-stage is now a 4-instruction LINEAR copy of the pre-swizzled ws image.
// Enc zero-fill interleave kept (R10 A/B: ~free vs +20.5us separate fill).
// ---------------------------------------------------------------------------
__global__ __launch_bounds__(256, 5)
void dist_mfma(const float* __restrict__ z_e,
               const unsigned char* __restrict__ ebf16g,
               const float* __restrict__ Bn_g, const float* __restrict__ maxbn,
               unsigned long long* __restrict__ lockey, float* __restrict__ out) {
    __shared__ unsigned short ebf[128 * 64];   // 16 KB bf16 codes, swizzled
    __shared__ float Bn_s[128];
    const int t = threadIdx.x, lane = t & 63, wv = t >> 6, g = lane >> 5;
    const int rg = blockIdx.x >> 3, cg = blockIdx.x & 7;
    const int n0 = rg * 128, b = n0 >> 10, hw0 = n0 & 1023;
    const float* zb = z_e + (size_t)b * 65536 + hw0;

    // ---- e-tile: linear copy of pre-swizzled bf16 image (16 KB) ----
    {
        const float4* ep = (const float4*)(ebf16g + (size_t)cg * 16384);
#pragma unroll
        for (int it = 0; it < 4; ++it) {
            float4 v = ep[it * 256 + t];
            *(float4*)((char*)ebf + (size_t)(it * 256 + t) * 16) = v;
        }
    }
    if (t < 128) Bn_s[t] = Bn_g[cg * 128 + t];    // bit-exact precomputed norms

    // ---- x B-fragments: straight from global to registers (no LDS) ----
    const int rowl = wv * 32 + (lane & 31);
    float xsq = 0.f;
    bf16x8 bfr[4];
#pragma unroll
    for (int s = 0; s < 4; ++s) {
        bf16x8 f;
#pragma unroll
        for (int e = 0; e < 8; ++e) {
            int d = s * 16 + g * 8 + e;
            float x = zb[(size_t)d * 1024 + rowl];
            xsq = __builtin_fmaf(x, x, xsq);
            f[e] = (short)f2bf(x);
        }
        bfr[s] = f;
    }
    xsq += __shfl_xor(xsq, 32, 64);          // partner half holds other 32 d's
    const float margin = 0.017f * sqrtf(xsq * maxbn[cg]) + 1.0e-4f;
    __syncthreads();

    const int swz = (lane & 7) << 4;
    const char* ebase = (const char*)ebf + (lane & 31) * 128;

    float4* encz = (float4*)(out + OUT_ENC) + (size_t)blockIdx.x * 4096;
    const float4 zero4 = make_float4(0.f, 0.f, 0.f, 0.f);

    // ---- pass 1: row min of s_hat (enc-fill stores ride along) ----
    float runmin = 3.4e38f;
#pragma unroll 1
    for (int tm = 0; tm < 4; ++tm) {
        encz[(size_t)(tm * 2 + 0) * 256 + t] = zero4;
        encz[(size_t)(tm * 2 + 1) * 256 + t] = zero4;
        const char* p = ebase + tm * 4096;
        f32x16 acc = {};
#pragma unroll
        for (int s = 0; s < 4; ++s)
            acc = __builtin_amdgcn_mfma_f32_32x32x16_bf16(
                *(const bf16x8*)(p + ((s * 32 + g * 16) ^ swz)), bfr[s], acc, 0, 0, 0);
#pragma unroll
        for (int r = 0; r < 16; ++r) {
            int cl = tm * 32 + (r & 3) + 8 * (r >> 2) + 4 * g;
            runmin = fminf(runmin, __builtin_fmaf(-2.f, acc[r], Bn_s[cl]));
        }
    }
    runmin = fminf(runmin, __shfl_xor(runmin, 32, 64));   // lane pair = same row
    const float thr = runmin + margin;

    // ---- pass 2: collect candidates (<=3/lane; MFMA recompute, cheap) ----
    uint32_t cnt = 0, c0 = 0, c1 = 0, c2 = 0;
#pragma unroll 1
    for (int tm = 0; tm < 4; ++tm) {
        encz[(size_t)(8 + tm * 2 + 0) * 256 + t] = zero4;
        encz[(size_t)(8 + tm * 2 + 1) * 256 + t] = zero4;
        const char* p = ebase + tm * 4096;
        f32x16 acc = {};
#pragma unroll
        for (int s = 0; s < 4; ++s)
            acc = __builtin_amdgcn_mfma_f32_32x32x16_bf16(
                *(const bf16x8*)(p + ((s * 32 + g * 16) ^ swz)), bfr[s], acc, 0, 0, 0);
#pragma unroll
        for (int r = 0; r < 16; ++r) {
            int cl = tm * 32 + (r & 3) + 8 * (r >> 2) + 4 * g;
            float sv = __builtin_fmaf(-2.f, acc[r], Bn_s[cl]);
            if (sv <= thr) {
                uint32_t gc = (uint32_t)(cg * 128 + cl);
                if (cnt == 0u) c0 = gc; else if (cnt == 1u) c1 = gc; else if (cnt == 2u) c2 = gc;
                ++cnt;
            }
        }
    }
    // merge with partner lane (lane^32: other code-subset of the same row)
    uint32_t pc = __shfl_xor(cnt, 32, 64);
    uint32_t p0 = __shfl_xor(c0, 32, 64);
    uint32_t p1 = __shfl_xor(c1, 32, 64);
    uint32_t p2 = __shfl_xor(c2, 32, 64);
    if (lane < 32) {
        uint32_t tot = cnt + pc;
        uint32_t lo;
        if (tot > 3u || tot == 0u) {
            lo = 3u << 30;                   // OVF marker for this cg
        } else {
            uint32_t a0 = c0, a1 = c1, a2 = c2;
            if (cnt == 0u)      { a0 = p0; a1 = p1; a2 = p2; }
            else if (cnt == 1u) { a1 = p0; a2 = p1; }
            else if (cnt == 2u) { a2 = p0; }
            if (tot < 2u) a1 = 0u;
            if (tot < 3u) a2 = 0u;
            lo = ((tot - 1u) << 30) | (a0 & 1023u) | ((a1 & 1023u) << 10) | ((a2 & 1023u) << 20);
        }
        unsigned long long key = ((unsigned long long)__float_as_uint(runmin) << 32) | lo;
        lockey[(size_t)(n0 + rowl) * 8 + cg] = key;
    }
}

// ---------------------------------------------------------------------------
// finish kernel (R13): 1024 blocks x 256 thr, 32 rows/block.
// PRUNE cgs by local_min > gmin + margin_global; 1-candidate fast path;
// parallel exact rechecks. OVF rows now scan ONLY the OVF'd cg's 128 codes
// (one exact_key per thread, t<128) and merge with the row's surviving
// candidates — the full-1024 scan remains only as the nc>6 fallback.
// exact_key_bn arithmetic bit-identical -> absmax 0.0.
// ---------------------------------------------------------------------------
__global__ __launch_bounds__(256)
void finish_kernel(const float* __restrict__ z_e, const float* __restrict__ emb,
                   const unsigned long long* __restrict__ lockey,
                   const float* __restrict__ Bn_g,
                   const float* __restrict__ maxbn,
                   uint32_t* __restrict__ counts, double* __restrict__ lp,
                   float* __restrict__ out) {
    __shared__ float zs[32 * 68];
    __shared__ float arow[32];                 // exact ||x||^2 per row
    __shared__ uint32_t scode[32];
    __shared__ uint8_t ncarr[32];              // 0=ovf-targeted,1=done,2..6=pairs,255=full
    __shared__ uint8_t ovfm[32];               // OVF cg mask (targeted rows)
    __shared__ uint8_t ovfnc[32];              // #cand pairs (targeted rows)
    __shared__ unsigned long long pkey[32][6];
    __shared__ unsigned long long okey[32];
    __shared__ uint32_t pairbuf[192];
    __shared__ uint32_t ovfbuf[32];
    __shared__ uint32_t npairs, novf;
    __shared__ float mbg_s;
    __shared__ unsigned long long rbuf[4];
    __shared__ double lred[4];
    const int t = threadIdx.x, lane = t & 63, wv = t >> 6;
    const int n0 = blockIdx.x * 32;                // rows n0..n0+31, same b
    const int b = n0 >> 10, hw0 = n0 & 1023;
    const int hwi = t & 31, dg = t >> 5;           // dg = 0..7
    const size_t base = (size_t)b * 65536 + (size_t)(dg * 8) * 1024 + hw0 + hwi;

    if (t == 0) {
        npairs = 0u; novf = 0u;
        float mb = maxbn[0];
#pragma unroll
        for (int i = 1; i < 8; ++i) mb = fmaxf(mb, maxbn[i]);
        mbg_s = mb;
    }

    // load z (coalesced 128B per quarter-wave), keep in regs, stage to LDS
    float zreg[8];
#pragma unroll
    for (int k = 0; k < 8; ++k) zreg[k] = z_e[base + (size_t)k * 1024];
#pragma unroll
    for (int m = 0; m < 2; ++m)
        *(float4*)&zs[hwi * 68 + dg * 8 + 4 * m] =
            make_float4(zreg[4 * m], zreg[4 * m + 1], zreg[4 * m + 2], zreg[4 * m + 3]);
    __syncthreads();

    // ---- decode: prune cgs, classify each row ----
    if (t < 32) {
        const unsigned long long* k8 = lockey + (size_t)(n0 + t) * 8;
        unsigned long long kws[8];
#pragma unroll
        for (int i = 0; i < 8; ++i) kws[i] = k8[i];
        float gmin = 3.4e38f;
#pragma unroll
        for (int i = 0; i < 8; ++i)
            gmin = fminf(gmin, __uint_as_float((uint32_t)(kws[i] >> 32)));
        float A = norm64v((const float4*)&zs[t * 68]);
        arow[t] = A;
        const float thr = gmin + 0.017f * sqrtf(A * mbg_s) + 1.0e-4f;

        int nc = 0; uint32_t cand[6]; uint32_t om = 0;
#pragma unroll
        for (int i = 0; i < 8; ++i) {
            float f = __uint_as_float((uint32_t)(kws[i] >> 32));
            if (f > thr) continue;              // prune: cg can't hold winner
            uint32_t lo = (uint32_t)kws[i], cc = lo >> 30;
            if (cc == 3u) { om |= (1u << i); }
            else {
#pragma unroll
                for (uint32_t q = 0; q < 3u; ++q)
                    if (q <= cc) {
                        if (nc < 6) cand[nc] = (lo >> (10u * q)) & 1023u;
                        ++nc;
                    }
            }
        }
        if (nc > 6 || (nc == 0 && om == 0u)) {
            ncarr[t] = 255u;                    // fallback: full 1024 scan
            ovfbuf[atomicAdd(&novf, 1u)] = (uint32_t)t;
        } else if (om) {
            ncarr[t] = 0u;                      // targeted OVF-cg scan
            ovfm[t] = (uint8_t)om;
            ovfnc[t] = (uint8_t)nc;
            ovfbuf[atomicAdd(&novf, 1u)] = (uint32_t)t;
            if (nc > 0) {
                uint32_t bs = atomicAdd(&npairs, (uint32_t)nc);
#pragma unroll
                for (int q = 0; q < 6; ++q)
                    if (q < nc)
                        pairbuf[bs + q] = ((uint32_t)t << 13) | ((uint32_t)q << 10) | cand[q];
            }
        } else if (nc == 1) {
            ncarr[t] = 1u;
            scode[t] = cand[0];                 // provably the numpy argmin
        } else {
            ncarr[t] = (uint8_t)nc;
            uint32_t bs = atomicAdd(&npairs, (uint32_t)nc);
#pragma unroll
            for (int q = 0; q < 6; ++q)
                if (q < nc)
                    pairbuf[bs + q] = ((uint32_t)t << 13) | ((uint32_t)q << 10) | cand[q];
        }
    }
    __syncthreads();

    // ---- parallel exact rechecks: one (row,code) per thread ----
    for (uint32_t p = t; p < npairs; p += 256u) {
        uint32_t pk = pairbuf[p];
        int row = (int)(pk >> 13), slot = (int)((pk >> 10) & 7u);
        pkey[row][slot] = exact_key_bn(arow[row], &zs[row * 68], emb, Bn_g, pk & 1023u);
    }
    __syncthreads();

    // ---- OVF rows: targeted per-cg 128-code scans (or full-scan fallback) ----
    for (uint32_t o = 0; o < novf; ++o) {
        int row = (int)ovfbuf[o];
        const float* xr = &zs[row * 68];
        float A = arow[row];
        unsigned long long best = ~0ULL;
        if (ncarr[row] == 255u) {
#pragma unroll 1
            for (int cq = 0; cq < 4; ++cq) {
                unsigned long long key = exact_key_bn(A, xr, emb, Bn_g, (uint32_t)(t + cq * 256));
                best = (key < best) ? key : best;
            }
        } else {
            uint32_t om = ovfm[row];
#pragma unroll 1
            for (int i = 0; i < 8; ++i) {
                if ((om & (1u << i)) && t < 128) {
                    unsigned long long key = exact_key_bn(A, xr, emb, Bn_g, (uint32_t)(i * 128 + t));
                    best = (key < best) ? key : best;
                }
            }
        }
#pragma unroll
        for (int m = 1; m < 64; m <<= 1) {
            unsigned long long ok = __shfl_xor(best, m, 64);
            best = (ok < best) ? ok : best;
        }
        if (lane == 0) rbuf[wv] = best;
        __syncthreads();
        if (t == 0) {
            unsigned long long bb = rbuf[0];
#pragma unroll
            for (int w = 1; w < 4; ++w) bb = (rbuf[w] < bb) ? rbuf[w] : bb;
            if (ncarr[row] == 255u) scode[row] = (uint32_t)bb;
            else                    okey[row] = bb;
        }
        __syncthreads();
    }

    // ---- resolve multi-candidate / targeted-OVF rows (numpy tie rule) ----
    if (t < 32) {
        uint8_t k = ncarr[t];
        if (k == 0u) {
            unsigned long long bb = okey[t];
            int nc = (int)ovfnc[t];
#pragma unroll
            for (int q = 0; q < 6; ++q)
                if (q < nc && pkey[t][q] < bb) bb = pkey[t][q];
            scode[t] = (uint32_t)bb;
        } else if (k >= 2u && k != 255u) {
            unsigned long long bb = pkey[t][0];
#pragma unroll
            for (int q = 1; q < 6; ++q)
                if (q < (int)k && pkey[t][q] < bb) bb = pkey[t][q];
            scode[t] = (uint32_t)bb;
        }
    }
    __syncthreads();

    if (t < 32) {
        uint32_t code = scode[t];
        atomicAdd(&counts[code], 1u);
        out[(size_t)OUT_ENC + (size_t)(n0 + t) * 1024 + code] = 1.0f;
    }

    // z_st + loss from registers (exact per-element math unchanged)
    {
        const uint32_t code = scode[hwi];
        const float4* er4 = (const float4*)(emb + (size_t)code * 64) + dg * 2;
        double ls = 0.0;
#pragma unroll
        for (int k4 = 0; k4 < 2; ++k4) {
            float4 e4 = er4[k4];
            float f0 = e4.x, f1 = e4.y, f2 = e4.z, f3 = e4.w;
            size_t off = base + (size_t)(k4 * 4) * 1024;
            {
                float z = zreg[k4 * 4 + 0]; float tt = f0 - z;
                out[off] = z + tt;              ls += (double)tt * (double)tt;
            }
            {
                float z = zreg[k4 * 4 + 1]; float tt = f1 - z;
                out[off + 1024] = z + tt;       ls += (double)tt * (double)tt;
            }
            {
                float z = zreg[k4 * 4 + 2]; float tt = f2 - z;
                out[off + 2048] = z + tt;       ls += (double)tt * (double)tt;
            }
            {
                float z = zreg[k4 * 4 + 3]; float tt = f3 - z;
                out[off + 3072] = z + tt;       ls += (double)tt * (double)tt;
            }
        }
#pragma unroll
        for (int m = 32; m >= 1; m >>= 1) ls += __shfl_down(ls, m, 64);
        if ((t & 63) == 0) lred[t >> 6] = ls;
    }
    __syncthreads();
    if (t == 0) lp[blockIdx.x] = lred[0] + lred[1] + lred[2] + lred[3];
}

// ---------------------------------------------------------------------------
// scalar kernel: one block; sum 1024 fp64 loss partials + counts entropy.
// Stream ordering (kernel boundary) provides coherence — no fence needed.
// ---------------------------------------------------------------------------
__global__ void scalar_kernel(const uint32_t* __restrict__ counts,
                              const double* __restrict__ lp,
                              float* __restrict__ out) {
    __shared__ double redl[4], redh[4];
    const int t = threadIdx.x;   // 256
    double ls = 0.0;
    for (int i = t; i < 1024; i += 256) ls += lp[i];
    double h = 0.0;
    for (int i = t; i < Kk; i += 256) {
        double p = (double)counts[i] * (1.0 / 32768.0);
        h += p * log(p + 1e-10);
    }
#pragma unroll
    for (int m = 32; m >= 1; m >>= 1) { ls += __shfl_down(ls, m, 64); h += __shfl_down(h, m, 64); }
    if ((t & 63) == 0) { redl[t >> 6] = ls; redh[t >> 6] = h; }
    __syncthreads();
    if (t == 0) {
        double L = redl[0] + redl[1] + redl[2] + redl[3];
        double H = redh[0] + redh[1] + redh[2] + redh[3];
        out[OUT_PERP] = (float)exp(-H);
        float m32 = (float)(L * (1.0 / 2097152.0));
        out[OUT_LOSS] = m32 + 0.25f * m32;   // q + 0.25*e, q==e numerically
    }
}

extern "C" void kernel_launch(void* const* d_in, const int* in_sizes, int n_in,
                              void* d_out, int out_size, void* d_ws, size_t ws_size,
                              hipStream_t stream) {
    const float* z_e = (const float*)d_in[0];
    const float* emb = (const float*)d_in[1];
    float* out = (float*)d_out;
    char* ws = (char*)d_ws;

    uint32_t* counts = (uint32_t*)(ws + WS_CNT);
    double*   lp     = (double*)(ws + WS_LP);
    float*    Bn_g   = (float*)(ws + WS_BN);
    float*    mbn    = (float*)(ws + WS_MBN);
    unsigned char* ebf16g = (unsigned char*)(ws + WS_EBF);
    unsigned long long* lockey = (unsigned long long*)(ws + WS_KEY);

    // no memsets: counts zeroed by norms block 0; Bn_g/maxbn/ebf16/lockey/lp
    // fully written; enc zeros laid down by dist's interleaved fill.
    norms_kernel<<<4, 256, 0, stream>>>(emb, Bn_g, mbn, counts, ebf16g);
    dist_mfma<<<2048, 256, 0, stream>>>(z_e, ebf16g, Bn_g, mbn, lockey, out);
    finish_kernel<<<1024, 256, 0, stream>>>(z_e, emb, lockey, Bn_g, mbn, counts, lp, out);
    scalar_kernel<<<1, 256, 0, stream>>>(counts, lp, out);
}

// Round 11
// 195.904 us; speedup vs baseline: 1.0323x; 1.0323x over previous
//
#include <hip/hip_runtime.h>
#include <stdint.h>
#include <math.h>

// Problem constants
constexpr int Kk  = 1024;

// d_out layout (floats)
constexpr int OUT0_N   = 32 * 64 * 1024;       // 2097152 (z_st, [B,D,H,W])
constexpr int OUT_LOSS = OUT0_N;               // 2097152
constexpr int OUT_PERP = OUT0_N + 1;           // 2097153
constexpr int OUT_ENC  = OUT0_N + 2;           // 2097154

// d_ws layout (bytes) — everything fully written each call (ws is poisoned):
//   [0      .. 4096)      counts u32[1024]     (zeroed by norms block 0)
//   [4096   .. 12288)     loss partials double[1024] (finish)
//   [12288  .. 16384)     Bn_g f32[1024]       exact code norms (norms_kernel)
//   [16384  .. 16400)     maxbn f32[4]         per-256-code-group max norm
//   [16400  .. 1064976)   lockey u64[32768][4] per-(row,cg): {local-min f32 hi,
//                         cnt+3x10b candidate codes lo} — PLAIN stores.
// R14 (base = R12, best at 197.1; R13's hoist/occ-5 reverted): cg split 8->4.
// 1024 dist blocks = EXACTLY 4 block-waves/CU — halves per-block overhead
// (stage+barrier+launch+x-load redundancy) at constant MFMA/store work.
// R15 = R14 resubmitted verbatim (R14 bench was an infra failure: container
// acquire failed twice; source re-audited — no hang/fault path found).
constexpr size_t WS_CNT = 0;
constexpr size_t WS_LP  = 4096;
constexpr size_t WS_BN  = 12288;
constexpr size_t WS_MBN = 16384;
constexpr size_t WS_KEY = 16400;

typedef short bf16x8 __attribute__((ext_vector_type(8)));
typedef float f32x16 __attribute__((ext_vector_type(16)));

// ---------------------------------------------------------------------------
// numpy-bit-exact 64-elem squared-norm: tt[d]=fl(x*x), 8 stride-8 sequential
// accumulators, pairwise combine. Contraction OFF. p: 16B-aligned, contiguous.
// ---------------------------------------------------------------------------
__device__ __forceinline__ float norm64v(const float4* __restrict__ p) {
#pragma clang fp contract(off)
    float tt[64];
#pragma unroll
    for (int q = 0; q < 16; ++q) {
        float4 v = p[q];
        tt[4 * q + 0] = v.x * v.x;
        tt[4 * q + 1] = v.y * v.y;
        tt[4 * q + 2] = v.z * v.z;
        tt[4 * q + 3] = v.w * v.w;
    }
    float r[8];
#pragma unroll
    for (int j = 0; j < 8; ++j) r[j] = tt[j];
#pragma unroll
    for (int i = 8; i < 64; i += 8)
#pragma unroll
        for (int j = 0; j < 8; ++j) r[j] += tt[i + j];
    return ((r[0] + r[1]) + (r[2] + r[3])) + ((r[4] + r[5]) + (r[6] + r[7]));
}

__device__ __forceinline__ uint32_t fsort(float f) {
    uint32_t b = __float_as_uint(f);
    return (b & 0x80000000u) ? ~b : (b | 0x80000000u);
}

// RNE float->bf16 (finite inputs only; data is well inside normal range)
__device__ __forceinline__ unsigned short f2bf(float f) {
    uint32_t u = __float_as_uint(f);
    uint32_t r = (u + 0x7fffu + ((u >> 16) & 1u)) >> 16;
    return (unsigned short)r;
}

// exact distance key, bit-identical arithmetic to R5/R7 (C = ascending-d
// sequential fma chain, single accumulator; dist = fl(fl(A+B)-2C)).
// emb row loaded as 16 float4s up front — FMA ORDER unchanged, only load
// scheduling improves (R11 lesson: divergent scalar gathers dominate).
__device__ __forceinline__ unsigned long long
exact_key_bn(float A, const float* __restrict__ xr, const float* __restrict__ emb,
             const float* __restrict__ Bn_g, uint32_t code) {
    const float4* e4 = (const float4*)(emb + (size_t)code * 64);
    float4 ev[16];
#pragma unroll
    for (int q = 0; q < 16; ++q) ev[q] = e4[q];
    float C = 0.f;
#pragma unroll
    for (int q = 0; q < 16; ++q) {
        C = __builtin_fmaf(xr[4 * q + 0], ev[q].x, C);
        C = __builtin_fmaf(xr[4 * q + 1], ev[q].y, C);
        C = __builtin_fmaf(xr[4 * q + 2], ev[q].z, C);
        C = __builtin_fmaf(xr[4 * q + 3], ev[q].w, C);
    }
    float s = A + Bn_g[code];
    float dist = __builtin_fmaf(-2.f, C, s);
    return ((unsigned long long)fsort(dist) << 32) | code;
}

// ---------------------------------------------------------------------------
// norms_kernel: 4 blocks x 256 thr — exact code norms ONCE, per-256-group max
// (one per block), counts zero.
// ---------------------------------------------------------------------------
__global__ __launch_bounds__(256)
void norms_kernel(const float* __restrict__ emb, float* __restrict__ Bn_g,
                  float* __restrict__ maxbn, uint32_t* __restrict__ counts) {
    __shared__ float wred[4];
    const int t = threadIdx.x, lane = t & 63, wv = t >> 6;
    const int code = blockIdx.x * 256 + t;
    float nn = norm64v((const float4*)(emb + (size_t)code * 64));
    Bn_g[code] = nn;
    if (blockIdx.x == 0) ((uint4*)counts)[t] = make_uint4(0u, 0u, 0u, 0u);
    float mx = nn;
#pragma unroll
    for (int m = 1; m < 64; m <<= 1) mx = fmaxf(mx, __shfl_xor(mx, m, 64));
    if (lane == 0) wred[wv] = mx;
    __syncthreads();
    if (t == 0)
        maxbn[blockIdx.x] = fmaxf(fmaxf(wred[0], wred[1]), fmaxf(wred[2], wred[3]));
}

// ---------------------------------------------------------------------------
// dist_mfma (R14): 1024 blocks = 256 rowgroups x 4 codegroups, 256 thr,
// ~33 KB LDS, 4 blocks/CU (launch_bounds(256,4): VGPR<=128) — EXACTLY 4
// block-waves/CU, halving R12's per-block overhead count.
// Screen: s_hat = Bn_exact - 2*(x.e)_bf16 via mfma_32x32x16_bf16; margin
// 0.017*sqrt(xsq*maxBn_cg)+1e-4 (validated R6/R8/R9/R12/R13, absmax 0.0).
// In-block fp32->bf16 e-conversion (R12 style; R13's ws-hoist reverted).
// Enc zero-fill interleave kept (R10 A/B: ~free vs separate fill dispatch).
// ---------------------------------------------------------------------------
__global__ __launch_bounds__(256, 4)
void dist_mfma(const float* __restrict__ z_e, const float* __restrict__ emb,
               const float* __restrict__ Bn_g, const float* __restrict__ maxbn,
               unsigned long long* __restrict__ lockey, float* __restrict__ out) {
    __shared__ unsigned short ebf[256 * 64];   // 32 KB bf16 codes, swizzled
    __shared__ float Bn_s[256];
    const int t = threadIdx.x, lane = t & 63, wv = t >> 6, g = lane >> 5;
    const int rg = blockIdx.x >> 2, cg = blockIdx.x & 3;
    const int n0 = rg * 128, b = n0 >> 10, hw0 = n0 & 1023;
    const float* zb = z_e + (size_t)b * 65536 + hw0;

    // ---- e-tile: contiguous 64 KB fp32 -> bf16 LDS (swizzled) ----
    {
        const float4* ep = (const float4*)(emb + (size_t)cg * 16384);
#pragma unroll
        for (int it = 0; it < 16; ++it) {
            int j = t + it * 256;            // 0..4095
            float4 v = ep[j];
            int code = j >> 4, q = j & 15;
            ushort4 bv;
            bv.x = f2bf(v.x); bv.y = f2bf(v.y); bv.z = f2bf(v.z); bv.w = f2bf(v.w);
            *(ushort4*)((char*)ebf + code * 128 + ((q * 8) ^ ((code & 7) << 4))) = bv;
        }
    }
    Bn_s[t] = Bn_g[cg * 256 + t];            // bit-exact precomputed norms

    // ---- x B-fragments: straight from global to registers (no LDS) ----
    const int rowl = wv * 32 + (lane & 31);
    float xsq = 0.f;
    bf16x8 bfr[4];
#pragma unroll
    for (int s = 0; s < 4; ++s) {
        bf16x8 f;
#pragma unroll
        for (int e = 0; e < 8; ++e) {
            int d = s * 16 + g * 8 + e;
            float x = zb[(size_t)d * 1024 + rowl];
            xsq = __builtin_fmaf(x, x, xsq);
            f[e] = (short)f2bf(x);
        }
        bfr[s] = f;
    }
    xsq += __shfl_xor(xsq, 32, 64);          // partner half holds other 32 d's
    const float margin = 0.017f * sqrtf(xsq * maxbn[cg]) + 1.0e-4f;
    __syncthreads();

    const int swz = (lane & 7) << 4;
    const char* ebase = (const char*)ebf + (lane & 31) * 128;

    // enc slice: rows n0..n0+127, f4-cols cg*64..cg*64+63 (1 KB/wave-instr)
    float* encp = out + OUT_ENC;
    const float4 zero4 = make_float4(0.f, 0.f, 0.f, 0.f);
    const int erow0 = t >> 6;                // store idx -> row = it*4 + erow0
    const int ec4 = t & 63;

    // ---- pass 1: row min of s_hat (2 enc-fill stores per tile ride along) ----
    float runmin = 3.4e38f;
#pragma unroll 1
    for (int tm = 0; tm < 8; ++tm) {
#pragma unroll
        for (int u = 0; u < 2; ++u) {
            int row = (tm * 2 + u) * 4 + erow0;          // 0..63
            ((float4*)(encp + (size_t)(n0 + row) * 1024 + cg * 256))[ec4] = zero4;
        }
        const char* p = ebase + tm * 4096;
        f32x16 acc = {};
#pragma unroll
        for (int s = 0; s < 4; ++s)
            acc = __builtin_amdgcn_mfma_f32_32x32x16_bf16(
                *(const bf16x8*)(p + ((s * 32 + g * 16) ^ swz)), bfr[s], acc, 0, 0, 0);
#pragma unroll
        for (int r = 0; r < 16; ++r) {
            int cl = tm * 32 + (r & 3) + 8 * (r >> 2) + 4 * g;
            runmin = fminf(runmin, __builtin_fmaf(-2.f, acc[r], Bn_s[cl]));
        }
    }
    runmin = fminf(runmin, __shfl_xor(runmin, 32, 64));   // lane pair = same row
    const float thr = runmin + margin;

    // ---- pass 2: collect candidates (<=3/lane; MFMA recompute, cheap) ----
    uint32_t cnt = 0, c0 = 0, c1 = 0, c2 = 0;
#pragma unroll 1
    for (int tm = 0; tm < 8; ++tm) {
#pragma unroll
        for (int u = 0; u < 2; ++u) {
            int row = 64 + (tm * 2 + u) * 4 + erow0;     // 64..127
            ((float4*)(encp + (size_t)(n0 + row) * 1024 + cg * 256))[ec4] = zero4;
        }
        const char* p = ebase + tm * 4096;
        f32x16 acc = {};
#pragma unroll
        for (int s = 0; s < 4; ++s)
            acc = __builtin_amdgcn_mfma_f32_32x32x16_bf16(
                *(const bf16x8*)(p + ((s * 32 + g * 16) ^ swz)), bfr[s], acc, 0, 0, 0);
#pragma unroll
        for (int r = 0; r < 16; ++r) {
            int cl = tm * 32 + (r & 3) + 8 * (r >> 2) + 4 * g;
            float sv = __builtin_fmaf(-2.f, acc[r], Bn_s[cl]);
            if (sv <= thr) {
                uint32_t gc = (uint32_t)(cg * 256 + cl);
                if (cnt == 0u) c0 = gc; else if (cnt == 1u) c1 = gc; else if (cnt == 2u) c2 = gc;
                ++cnt;
            }
        }
    }
    // merge with partner lane (lane^32: other code-subset of the same row)
    uint32_t pc = __shfl_xor(cnt, 32, 64);
    uint32_t p0 = __shfl_xor(c0, 32, 64);
    uint32_t p1 = __shfl_xor(c1, 32, 64);
    uint32_t p2 = __shfl_xor(c2, 32, 64);
    if (lane < 32) {
        uint32_t tot = cnt + pc;
        uint32_t lo;
        if (tot > 3u || tot == 0u) {
            lo = 3u << 30;                   // OVF marker for this cg
        } else {
            uint32_t a0 = c0, a1 = c1, a2 = c2;
            if (cnt == 0u)      { a0 = p0; a1 = p1; a2 = p2; }
            else if (cnt == 1u) { a1 = p0; a2 = p1; }
            else if (cnt == 2u) { a2 = p0; }
            if (tot < 2u) a1 = 0u;
            if (tot < 3u) a2 = 0u;
            lo = ((tot - 1u) << 30) | (a0 & 1023u) | ((a1 & 1023u) << 10) | ((a2 & 1023u) << 20);
        }
        unsigned long long key = ((unsigned long long)__float_as_uint(runmin) << 32) | lo;
        lockey[(size_t)(n0 + rowl) * 4 + cg] = key;
    }
}

// ---------------------------------------------------------------------------
// finish kernel (R14): 1024 blocks x 256 thr, 32 rows/block.
// PRUNE cgs by local_min > gmin + margin_global; 1-candidate fast path;
// parallel exact rechecks. OVF rows scan ONLY the OVF'd cg's 256 codes —
// exactly one exact_key per thread. Full-1024 scan only as nc>6 fallback.
// exact_key_bn / norm64v / key+tie rule bit-identical -> absmax 0.0.
// ---------------------------------------------------------------------------
__global__ __launch_bounds__(256)
void finish_kernel(const float* __restrict__ z_e, const float* __restrict__ emb,
                   const unsigned long long* __restrict__ lockey,
                   const float* __restrict__ Bn_g,
                   const float* __restrict__ maxbn,
                   uint32_t* __restrict__ counts, double* __restrict__ lp,
                   float* __restrict__ out) {
    __shared__ float zs[32 * 68];
    __shared__ float arow[32];                 // exact ||x||^2 per row
    __shared__ uint32_t scode[32];
    __shared__ uint8_t ncarr[32];              // 0=ovf-targeted,1=done,2..6=pairs,255=full
    __shared__ uint8_t ovfm[32];               // OVF cg mask (targeted rows)
    __shared__ uint8_t ovfnc[32];              // #cand pairs (targeted rows)
    __shared__ unsigned long long pkey[32][6];
    __shared__ unsigned long long okey[32];
    __shared__ uint32_t pairbuf[192];
    __shared__ uint32_t ovfbuf[32];
    __shared__ uint32_t npairs, novf;
    __shared__ float mbg_s;
    __shared__ unsigned long long rbuf[4];
    __shared__ double lred[4];
    const int t = threadIdx.x, lane = t & 63, wv = t >> 6;
    const int n0 = blockIdx.x * 32;                // rows n0..n0+31, same b
    const int b = n0 >> 10, hw0 = n0 & 1023;
    const int hwi = t & 31, dg = t >> 5;           // dg = 0..7
    const size_t base = (size_t)b * 65536 + (size_t)(dg * 8) * 1024 + hw0 + hwi;

    if (t == 0) {
        npairs = 0u; novf = 0u;
        float mb = fmaxf(fmaxf(maxbn[0], maxbn[1]), fmaxf(maxbn[2], maxbn[3]));
        mbg_s = mb;
    }

    // load z (coalesced 128B per quarter-wave), keep in regs, stage to LDS
    float zreg[8];
#pragma unroll
    for (int k = 0; k < 8; ++k) zreg[k] = z_e[base + (size_t)k * 1024];
#pragma unroll
    for (int m = 0; m < 2; ++m)
        *(float4*)&zs[hwi * 68 + dg * 8 + 4 * m] =
            make_float4(zreg[4 * m], zreg[4 * m + 1], zreg[4 * m + 2], zreg[4 * m + 3]);
    __syncthreads();

    // ---- decode: prune cgs, classify each row ----
    if (t < 32) {
        const unsigned long long* k4 = lockey + (size_t)(n0 + t) * 4;
        unsigned long long kws[4];
#pragma unroll
        for (int i = 0; i < 4; ++i) kws[i] = k4[i];
        float gmin = 3.4e38f;
#pragma unroll
        for (int i = 0; i < 4; ++i)
            gmin = fminf(gmin, __uint_as_float((uint32_t)(kws[i] >> 32)));
        float A = norm64v((const float4*)&zs[t * 68]);
        arow[t] = A;
        const float thr = gmin + 0.017f * sqrtf(A * mbg_s) + 1.0e-4f;

        int nc = 0; uint32_t cand[6]; uint32_t om = 0;
#pragma unroll
        for (int i = 0; i < 4; ++i) {
            float f = __uint_as_float((uint32_t)(kws[i] >> 32));
            if (f > thr) continue;              // prune: cg can't hold winner
            uint32_t lo = (uint32_t)kws[i], cc = lo >> 30;
            if (cc == 3u) { om |= (1u << i); }
            else {
#pragma unroll
                for (uint32_t q = 0; q < 3u; ++q)
                    if (q <= cc) {
                        if (nc < 6) cand[nc] = (lo >> (10u * q)) & 1023u;
                        ++nc;
                    }
            }
        }
        if (nc > 6 || (nc == 0 && om == 0u)) {
            ncarr[t] = 255u;                    // fallback: full 1024 scan
            ovfbuf[atomicAdd(&novf, 1u)] = (uint32_t)t;
        } else if (om) {
            ncarr[t] = 0u;                      // targeted OVF-cg scan
            ovfm[t] = (uint8_t)om;
            ovfnc[t] = (uint8_t)nc;
            ovfbuf[atomicAdd(&novf, 1u)] = (uint32_t)t;
            if (nc > 0) {
                uint32_t bs = atomicAdd(&npairs, (uint32_t)nc);
#pragma unroll
                for (int q = 0; q < 6; ++q)
                    if (q < nc)
                        pairbuf[bs + q] = ((uint32_t)t << 13) | ((uint32_t)q << 10) | cand[q];
            }
        } else if (nc == 1) {
            ncarr[t] = 1u;
            scode[t] = cand[0];                 // provably the numpy argmin
        } else {
            ncarr[t] = (uint8_t)nc;
            uint32_t bs = atomicAdd(&npairs, (uint32_t)nc);
#pragma unroll
            for (int q = 0; q < 6; ++q)
                if (q < nc)
                    pairbuf[bs + q] = ((uint32_t)t << 13) | ((uint32_t)q << 10) | cand[q];
        }
    }
    __syncthreads();

    // ---- parallel exact rechecks: one (row,code) per thread ----
    for (uint32_t p = t; p < npairs; p += 256u) {
        uint32_t pk = pairbuf[p];
        int row = (int)(pk >> 13), slot = (int)((pk >> 10) & 7u);
        pkey[row][slot] = exact_key_bn(arow[row], &zs[row * 68], emb, Bn_g, pk & 1023u);
    }
    __syncthreads();

    // ---- OVF rows: targeted per-cg 256-code scans (1 key/thread) ----
    for (uint32_t o = 0; o < novf; ++o) {
        int row = (int)ovfbuf[o];
        const float* xr = &zs[row * 68];
        float A = arow[row];
        unsigned long long best = ~0ULL;
        if (ncarr[row] == 255u) {
#pragma unroll 1
            for (int cq = 0; cq < 4; ++cq) {
                unsigned long long key = exact_key_bn(A, xr, emb, Bn_g, (uint32_t)(t + cq * 256));
                best = (key < best) ? key : best;
            }
        } else {
            uint32_t om = ovfm[row];
#pragma unroll 1
            for (int i = 0; i < 4; ++i) {
                if (om & (1u << i)) {
                    unsigned long long key = exact_key_bn(A, xr, emb, Bn_g, (uint32_t)(i * 256 + t));
                    best = (key < best) ? key : best;
                }
            }
        }
#pragma unroll
        for (int m = 1; m < 64; m <<= 1) {
            unsigned long long ok = __shfl_xor(best, m, 64);
            best = (ok < best) ? ok : best;
        }
        if (lane == 0) rbuf[wv] = best;
        __syncthreads();
        if (t == 0) {
            unsigned long long bb = rbuf[0];
#pragma unroll
            for (int w = 1; w < 4; ++w) bb = (rbuf[w] < bb) ? rbuf[w] : bb;
            if (ncarr[row] == 255u) scode[row] = (uint32_t)bb;
            else                    okey[row] = bb;
        }
        __syncthreads();
    }

    // ---- resolve multi-candidate / targeted-OVF rows (numpy tie rule) ----
    if (t < 32) {
        uint8_t k = ncarr[t];
        if (k == 0u) {
            unsigned long long bb = okey[t];
            int nc = (int)ovfnc[t];
#pragma unroll
            for (int q = 0; q < 6; ++q)
                if (q < nc && pkey[t][q] < bb) bb = pkey[t][q];
            scode[t] = (uint32_t)bb;
        } else if (k >= 2u && k != 255u) {
            unsigned long long bb = pkey[t][0];
#pragma unroll
            for (int q = 1; q < 6; ++q)
                if (q < (int)k && pkey[t][q] < bb) bb = pkey[t][q];
            scode[t] = (uint32_t)bb;
        }
    }
    __syncthreads();

    if (t < 32) {
        uint32_t code = scode[t];
        atomicAdd(&counts[code], 1u);
        out[(size_t)OUT_ENC + (size_t)(n0 + t) * 1024 + code] = 1.0f;
    }

    // z_st + loss from registers (exact per-element math unchanged)
    {
        const uint32_t code = scode[hwi];
        const float4* er4 = (const float4*)(emb + (size_t)code * 64) + dg * 2;
        double ls = 0.0;
#pragma unroll
        for (int k4 = 0; k4 < 2; ++k4) {
            float4 e4 = er4[k4];
            float f0 = e4.x, f1 = e4.y, f2 = e4.z, f3 = e4.w;
            size_t off = base + (size_t)(k4 * 4) * 1024;
            {
                float z = zreg[k4 * 4 + 0]; float tt = f0 - z;
                out[off] = z + tt;              ls += (double)tt * (double)tt;
            }
            {
                float z = zreg[k4 * 4 + 1]; float tt = f1 - z;
                out[off + 1024] = z + tt;       ls += (double)tt * (double)tt;
            }
            {
                float z = zreg[k4 * 4 + 2]; float tt = f2 - z;
                out[off + 2048] = z + tt;       ls += (double)tt * (double)tt;
            }
            {
                float z = zreg[k4 * 4 + 3]; float tt = f3 - z;
                out[off + 3072] = z + tt;       ls += (double)tt * (double)tt;
            }
        }
#pragma unroll
        for (int m = 32; m >= 1; m >>= 1) ls += __shfl_down(ls, m, 64);
        if ((t & 63) == 0) lred[t >> 6] = ls;
    }
    __syncthreads();
    if (t == 0) lp[blockIdx.x] = lred[0] + lred[1] + lred[2] + lred[3];
}

// ---------------------------------------------------------------------------
// scalar kernel: one block; sum 1024 fp64 loss partials + counts entropy.
// Stream ordering (kernel boundary) provides coherence — no fence needed.
// ---------------------------------------------------------------------------
__global__ void scalar_kernel(const uint32_t* __restrict__ counts,
                              const double* __restrict__ lp,
                              float* __restrict__ out) {
    __shared__ double redl[4], redh[4];
    const int t = threadIdx.x;   // 256
    double ls = 0.0;
    for (int i = t; i < 1024; i += 256) ls += lp[i];
    double h = 0.0;
    for (int i = t; i < Kk; i += 256) {
        double p = (double)counts[i] * (1.0 / 32768.0);
        h += p * log(p + 1e-10);
    }
#pragma unroll
    for (int m = 32; m >= 1; m >>= 1) { ls += __shfl_down(ls, m, 64); h += __shfl_down(h, m, 64); }
    if ((t & 63) == 0) { redl[t >> 6] = ls; redh[t >> 6] = h; }
    __syncthreads();
    if (t == 0) {
        double L = redl[0] + redl[1] + redl[2] + redl[3];
        double H = redh[0] + redh[1] + redh[2] + redh[3];
        out[OUT_PERP] = (float)exp(-H);
        float m32 = (float)(L * (1.0 / 2097152.0));
        out[OUT_LOSS] = m32 + 0.25f * m32;   // q + 0.25*e, q==e numerically
    }
}

extern "C" void kernel_launch(void* const* d_in, const int* in_sizes, int n_in,
                              void* d_out, int out_size, void* d_ws, size_t ws_size,
                              hipStream_t stream) {
    const float* z_e = (const float*)d_in[0];
    const float* emb = (const float*)d_in[1];
    float* out = (float*)d_out;
    char* ws = (char*)d_ws;

    uint32_t* counts = (uint32_t*)(ws + WS_CNT);
    double*   lp     = (double*)(ws + WS_LP);
    float*    Bn_g   = (float*)(ws + WS_BN);
    float*    mbn    = (float*)(ws + WS_MBN);
    unsigned long long* lockey = (unsigned long long*)(ws + WS_KEY);

    // no memsets: counts zeroed by norms block 0; Bn_g/maxbn/lockey/lp fully
    // written; enc zeros laid down by dist's interleaved fill.
    norms_kernel<<<4, 256, 0, stream>>>(emb, Bn_g, mbn, counts);
    dist_mfma<<<1024, 256, 0, stream>>>(z_e, emb, Bn_g, mbn, lockey, out);
    finish_kernel<<<1024, 256, 0, stream>>>(z_e, emb, lockey, Bn_g, mbn, counts, lp, out);
    scalar_kernel<<<1, 256, 0, stream>>>(counts, lp, out);
}